// Round 3
// baseline (264.214 us; speedup 1.0000x reference)
//
#include <hip/hip_runtime.h>
#include <hip/hip_bf16.h>
#include <stdint.h>

// ============================================================================
// AdaptiveEdgeDropping: out = matrix with top-k (k = E*pct/100) of
// (log_sigmoid(dp*(1-v) - g*v) + gumbel(key=42)) zeroed.  BIT-EXACT.
//
// Strategy (round 3): approximate keys with HW transcendentals for all E
// elements (|approx-exact| <= ~1e-5 provable), radix-select a threshold
// bracket on approx keys, then evaluate the exact Cephes chain ONLY for the
// ~10-40K elements within +-DELTA of the bracket and select among them with
// an exact 16+16-bit radix select (stable ties by lowest index).
// Fallback (ws too small for a key buffer): exact keys everywhere, DELTA=0.
// ============================================================================

#define LIST_CAP 262144u
#define MINI_CAP 4096u
#define DELTA 1e-3f

// ---------------- threefry2x32, key=(0,42), counts=(0,i), out = x0^x1 -------
__device__ __forceinline__ unsigned tf_bits(unsigned i) {
  const unsigned ks0 = 0u;
  const unsigned ks1 = 42u;
  const unsigned ks2 = 0x1BD11BDAu ^ 0u ^ 42u;
  unsigned x0 = 0u + ks0;
  unsigned x1 = i + ks1;
#define TF_R(rot) { x0 += x1; x1 = (x1 << (rot)) | (x1 >> (32 - (rot))); x1 ^= x0; }
  TF_R(13) TF_R(15) TF_R(26) TF_R(6)
  x0 += ks1; x1 += ks2 + 1u;
  TF_R(17) TF_R(29) TF_R(16) TF_R(24)
  x0 += ks2; x1 += ks0 + 2u;
  TF_R(13) TF_R(15) TF_R(26) TF_R(6)
  x0 += ks0; x1 += ks1 + 3u;
  TF_R(17) TF_R(29) TF_R(16) TF_R(24)
  x0 += ks1; x1 += ks2 + 4u;
  TF_R(13) TF_R(15) TF_R(26) TF_R(6)
  x0 += ks2; x1 += ks0 + 5u;
#undef TF_R
  return x0 ^ x1;
}

// ---------------- jax.random.uniform(minval=1e-7, maxval=1-1e-7) -----------
__device__ __forceinline__ float uniform_from_bits(unsigned bits) {
  unsigned fb = (bits >> 9) | 0x3f800000u;
  float f = __uint_as_float(fb) - 1.0f;
  const float minv = 1e-7f;
  const float maxv = __uint_as_float(0x3F7FFFFEu);   // f32(1.0 - 1e-7)
  float r = __fsub_rn(maxv, minv);
  float u = __fadd_rn(__fmul_rn(f, r), minv);
  return fmaxf(minv, u);
}

// ---------------- XLA-CPU Cephes expf (unfused) ----------------------------
__device__ __forceinline__ float xla_expf(float input) {
  const float exp_hi = 88.3762626647950f;
  const float exp_lo = -88.3762626647949f;
  float x = fminf(fmaxf(input, exp_lo), exp_hi);
  float fx = floorf(__fadd_rn(__fmul_rn(x, 1.44269504088896341f), 0.5f));
  float tmp = __fmul_rn(0.693359375f, fx);
  float z = __fmul_rn(-2.12194440e-4f, fx);
  x = __fsub_rn(x, tmp);
  x = __fsub_rn(x, z);
  z = __fmul_rn(x, x);
  float y = __fadd_rn(__fmul_rn(x, 1.9875691500e-4f), 1.3981999507e-3f);
  y = __fadd_rn(__fmul_rn(y, x), 8.3334519073e-3f);
  y = __fadd_rn(__fmul_rn(y, x), 4.1665795894e-2f);
  y = __fadd_rn(__fmul_rn(y, x), 1.6666665459e-1f);
  y = __fadd_rn(__fmul_rn(y, x), 5.0000001201e-1f);
  y = __fadd_rn(__fmul_rn(y, z), x);
  y = __fadd_rn(1.0f, y);
  int n = (int)fx;
  float p2n = __int_as_float((n + 0x7f) << 23);
  return fmaxf(__fmul_rn(y, p2n), input);
}

// ---------------- XLA-CPU Cephes logf (Estrin, unfused) --------------------
__device__ __forceinline__ float xla_logf(float input) {
  float t0 = fmaxf(input, __uint_as_float(0x00800000u));
  unsigned ib = __float_as_uint(t0);
  int emm0 = (int)(ib >> 23) - 0x7f;
  float e = __fadd_rn(1.0f, (float)emm0);
  float m = __uint_as_float((ib & 0x807fffffu) | 0x3f000000u);
  bool mask = m < 0.707106781186547524f;
  float t1 = mask ? m : 0.0f;
  m = __fsub_rn(m, 1.0f);
  e = __fsub_rn(e, mask ? 1.0f : 0.0f);
  m = __fadd_rn(m, t1);
  float x2 = __fmul_rn(m, m);
  float x3 = __fmul_rn(x2, m);
  float y  = __fadd_rn(__fmul_rn(m, 7.0376836292e-2f), -1.1514610310e-1f);
  float y1 = __fadd_rn(__fmul_rn(m, -1.2420140846e-1f), 1.4249322787e-1f);
  float y2 = __fadd_rn(__fmul_rn(m, 2.0000714765e-1f), -2.4999993993e-1f);
  y  = __fadd_rn(__fmul_rn(y, m), 1.1676998740e-1f);
  y1 = __fadd_rn(__fmul_rn(y1, m), -1.6668057665e-1f);
  y2 = __fadd_rn(__fmul_rn(y2, m), 3.3333331174e-1f);
  y = __fadd_rn(__fmul_rn(y, x3), y1);
  y = __fadd_rn(__fmul_rn(y, x3), y2);
  y = __fmul_rn(y, x3);
  y = __fadd_rn(y, __fmul_rn(-2.12194440e-4f, e));
  y = __fsub_rn(y, __fmul_rn(0.5f, x2));
  m = __fadd_rn(m, y);
  m = __fadd_rn(m, __fmul_rn(0.693359375f, e));
  return m;
}

// ---------------- XLA elemental log1p --------------------------------------
__device__ __forceinline__ float xla_log1pf(float x) {
  float for_large = xla_logf(__fadd_rn(x, 1.0f));
  float for_small = __fmul_rn(__fadd_rn(__fmul_rn(-0.5f, x), 1.0f), x);
  return (fabsf(x) < 1e-4f) ? for_small : for_large;
}

// ---------------- monotone code <-> float ----------------------------------
__device__ __forceinline__ unsigned encode_f(float f) {
  unsigned b = __float_as_uint(f);
  return (b & 0x80000000u) ? ~b : (b | 0x80000000u);
}
__device__ __forceinline__ float decode_f(unsigned c) {
  unsigned b = (c & 0x80000000u) ? (c ^ 0x80000000u) : ~c;
  return __uint_as_float(b);
}

// ---------------- EXACT per-element key code (verified bit-exact) ----------
__device__ __forceinline__ unsigned compute_ou(unsigned i, float v, float dp, float g) {
  if (v == 0.0f) return 0u;
  unsigned bits = tf_bits(i);
  float u = uniform_from_bits(bits);
  float lg = xla_logf(u);
  float gum = -xla_logf(-lg);
  float t = __fsub_rn(1.0f, v);
  float lx = __fsub_rn(__fmul_rn(dp, t), __fmul_rn(g, v));
  float ex = xla_expf(-fabsf(lx));
  float l1p = xla_log1pf(ex);
  float lp = -(__fadd_rn(fmaxf(-lx, 0.0f), l1p));
  float key = __fadd_rn(lp, gum);
  return encode_f(key);
}

// ---------------- APPROX key code (HW transcendentals, |err| <= ~1e-5) -----
__device__ __forceinline__ unsigned approx_code(unsigned i, float v, float dp, float g) {
  if (v == 0.0f) return 0u;
  unsigned bits = tf_bits(i);
  float u = uniform_from_bits(bits);        // exact (same as exact path)
  float lg = __logf(u);                     // hw: rel err ~1ulp
  float gum = -__logf(-lg);                 // abs err ~ rel err of lg
  float t = __fsub_rn(1.0f, v);
  float lx = __fsub_rn(__fmul_rn(dp, t), __fmul_rn(g, v));  // identical to exact
  float ex = __expf(-fabsf(lx));
  float for_small = __fmul_rn(__fadd_rn(__fmul_rn(-0.5f, ex), 1.0f), ex); // identical
  float l1p = (fabsf(ex) < 1e-4f) ? for_small : __logf(__fadd_rn(ex, 1.0f));
  float lp = -(__fadd_rn(fmaxf(-lx, 0.0f), l1p));
  float key = __fadd_rn(lp, gum);
  return encode_f(key);
}

// ============================================================================
// P1: keys (approx if stored, exact if not), LDS hist of top-12 code bits.
// ============================================================================
__global__ __launch_bounds__(512) void key_hist1_kernel(
    const float* __restrict__ v, const float* __restrict__ dpp,
    const float* __restrict__ gp, unsigned* __restrict__ keys,
    unsigned* __restrict__ blockhist, int E) {
  __shared__ unsigned h[4096];
  for (int j = threadIdx.x; j < 4096; j += 512) h[j] = 0;
  __syncthreads();
  float dp = dpp[0], g = gp[0];
  int nvec = E >> 2;
  int stride = gridDim.x * blockDim.x;
  for (int iv = blockIdx.x * blockDim.x + threadIdx.x; iv < nvec; iv += stride) {
    float4 vv = reinterpret_cast<const float4*>(v)[iv];
    unsigned base = (unsigned)iv << 2;
    unsigned o0, o1, o2, o3;
    if (keys) {
      o0 = approx_code(base + 0u, vv.x, dp, g);
      o1 = approx_code(base + 1u, vv.y, dp, g);
      o2 = approx_code(base + 2u, vv.z, dp, g);
      o3 = approx_code(base + 3u, vv.w, dp, g);
      reinterpret_cast<uint4*>(keys)[iv] = make_uint4(o0, o1, o2, o3);
    } else {
      o0 = compute_ou(base + 0u, vv.x, dp, g);
      o1 = compute_ou(base + 1u, vv.y, dp, g);
      o2 = compute_ou(base + 2u, vv.z, dp, g);
      o3 = compute_ou(base + 3u, vv.w, dp, g);
    }
    atomicAdd(&h[o0 >> 20], 1u);
    atomicAdd(&h[o1 >> 20], 1u);
    atomicAdd(&h[o2 >> 20], 1u);
    atomicAdd(&h[o3 >> 20], 1u);
  }
  if (blockIdx.x == 0) {
    for (int i = (nvec << 2) + threadIdx.x; i < E; i += 512) {
      float val = v[i];
      unsigned ou = keys ? approx_code((unsigned)i, val, dp, g)
                         : compute_ou((unsigned)i, val, dp, g);
      if (keys) keys[i] = ou;
      atomicAdd(&h[ou >> 20], 1u);
    }
  }
  __syncthreads();
  unsigned* row = blockhist + (size_t)blockIdx.x * 4096;
  for (int j = threadIdx.x; j < 4096; j += 512) row[j] = h[j];
}

// ============================================================================
// P2: histogram bits [8..20) of coarse-bin-B1 members.
// ============================================================================
__global__ __launch_bounds__(512) void refine_hist_kernel(
    const float* __restrict__ v, const float* __restrict__ dpp,
    const float* __restrict__ gp, const unsigned* __restrict__ keys,
    const unsigned* __restrict__ state, unsigned* __restrict__ blockhist, int E) {
  __shared__ unsigned h[4096];
  for (int j = threadIdx.x; j < 4096; j += 512) h[j] = 0;
  __syncthreads();
  unsigned B1 = state[0];
  float dp = dpp[0], g = gp[0];
  int nvec = E >> 2;
  int stride = gridDim.x * blockDim.x;
  for (int iv = blockIdx.x * blockDim.x + threadIdx.x; iv < nvec; iv += stride) {
    unsigned o0, o1, o2, o3;
    if (keys) {
      uint4 kk = reinterpret_cast<const uint4*>(keys)[iv];
      o0 = kk.x; o1 = kk.y; o2 = kk.z; o3 = kk.w;
    } else {
      float4 vv = reinterpret_cast<const float4*>(v)[iv];
      unsigned base = (unsigned)iv << 2;
      o0 = compute_ou(base + 0u, vv.x, dp, g);
      o1 = compute_ou(base + 1u, vv.y, dp, g);
      o2 = compute_ou(base + 2u, vv.z, dp, g);
      o3 = compute_ou(base + 3u, vv.w, dp, g);
    }
    if ((o0 >> 20) == B1) atomicAdd(&h[(o0 >> 8) & 0xFFFu], 1u);
    if ((o1 >> 20) == B1) atomicAdd(&h[(o1 >> 8) & 0xFFFu], 1u);
    if ((o2 >> 20) == B1) atomicAdd(&h[(o2 >> 8) & 0xFFFu], 1u);
    if ((o3 >> 20) == B1) atomicAdd(&h[(o3 >> 8) & 0xFFFu], 1u);
  }
  if (blockIdx.x == 0) {
    for (int i = (nvec << 2) + threadIdx.x; i < E; i += 512) {
      unsigned ou = keys ? keys[i] : compute_ou((unsigned)i, v[i], dp, g);
      if ((ou >> 20) == B1) atomicAdd(&h[(ou >> 8) & 0xFFFu], 1u);
    }
  }
  __syncthreads();
  unsigned* row = blockhist + (size_t)blockIdx.x * 4096;
  for (int j = threadIdx.x; j < 4096; j += 512) row[j] = h[j];
}

// ============================================================================
// R: hist[j] += sum_b blockhist[b][j]   (hist pre-zeroed)
// ============================================================================
#define RED_SLICES 8
__global__ __launch_bounds__(256) void reduce_hist_kernel(
    const unsigned* __restrict__ blockhist, unsigned* __restrict__ hist, int NB) {
  int gid = blockIdx.x * 256 + threadIdx.x;
  int j = gid & 4095;
  int slice = gid >> 12;
  unsigned s = 0;
  for (int b = slice; b < NB; b += RED_SLICES)
    s += blockhist[(size_t)b * 4096 + j];
  atomicAdd(&hist[j], s);
}

// ============================================================================
// F1: level-1 select. state[0]=B1, state[1]=r1, state[6]=k. Zeroes hist.
// ============================================================================
__global__ __launch_bounds__(1024) void find1_kernel(
    unsigned* __restrict__ hist, unsigned* __restrict__ state,
    const int* __restrict__ pct_p, long long Etot) {
  __shared__ unsigned s[1024];
  int t = threadIdx.x;
  unsigned h0 = hist[4 * t + 0], h1 = hist[4 * t + 1];
  unsigned h2 = hist[4 * t + 2], h3 = hist[4 * t + 3];
  unsigned tot = h0 + h1 + h2 + h3;
  s[t] = tot;
  __syncthreads();
  for (int off = 1; off < 1024; off <<= 1) {
    unsigned add = (t + off < 1024) ? s[t + off] : 0u;
    __syncthreads();
    s[t] += add;
    __syncthreads();
  }
  long long k = (Etot * (long long)pct_p[0]) / 100;
  long long above_next = (t < 1023) ? (long long)s[t + 1] : 0;
  if (above_next < k && k <= above_next + (long long)tot) {
    unsigned hh[4] = {h0, h1, h2, h3};
    long long above = above_next;
    int b = 3;
    for (; b >= 0; --b) {
      if (above < k && k <= above + (long long)hh[b]) break;
      above += (long long)hh[b];
    }
    state[0] = (unsigned)(4 * t + b);
    state[1] = (unsigned)(k - above);
    state[6] = (unsigned)k;
  }
  hist[4 * t + 0] = 0u; hist[4 * t + 1] = 0u;
  hist[4 * t + 2] = 0u; hist[4 * t + 3] = 0u;
}

// ============================================================================
// F2: level-2 select -> 24-bit prefix P -> band codes with +-delta margin.
// state[2]=band_lo_code, state[3]=band_hi_code.
// ============================================================================
__global__ __launch_bounds__(1024) void find2_kernel(
    const unsigned* __restrict__ hist, unsigned* __restrict__ state, float delta) {
  __shared__ unsigned s[1024];
  int t = threadIdx.x;
  unsigned h0 = hist[4 * t + 0], h1 = hist[4 * t + 1];
  unsigned h2 = hist[4 * t + 2], h3 = hist[4 * t + 3];
  unsigned tot = h0 + h1 + h2 + h3;
  s[t] = tot;
  __syncthreads();
  for (int off = 1; off < 1024; off <<= 1) {
    unsigned add = (t + off < 1024) ? s[t + off] : 0u;
    __syncthreads();
    s[t] += add;
    __syncthreads();
  }
  long long k2 = (long long)state[1];
  long long above_next = (t < 1023) ? (long long)s[t + 1] : 0;
  if (above_next < k2 && k2 <= above_next + (long long)tot) {
    unsigned hh[4] = {h0, h1, h2, h3};
    long long above = above_next;
    int b = 3;
    for (; b >= 0; --b) {
      if (above < k2 && k2 <= above + (long long)hh[b]) break;
      above += (long long)hh[b];
    }
    unsigned P = (state[0] << 12) | (unsigned)(4 * t + b);
    float L = decode_f(P << 8);          // smallest key value in bin P
    float H = decode_f((P + 1u) << 8);   // smallest key value in bin P+1
    state[2] = encode_f(L - delta);
    state[3] = encode_f(H + delta);
  }
}

// ============================================================================
// P3: write output (code > band_hi -> 0); band members -> exact eval + list +
// ehist1; count |A| per-block.
// ============================================================================
__global__ __launch_bounds__(512) void output_kernel(
    const float* __restrict__ v, const float* __restrict__ dpp,
    const float* __restrict__ gp, const unsigned* __restrict__ keys,
    float* __restrict__ out, unsigned* __restrict__ state,
    uint2* __restrict__ list, unsigned* __restrict__ ehist1, int E) {
  __shared__ unsigned sacc;
  if (threadIdx.x == 0) sacc = 0;
  __syncthreads();
  unsigned blo = state[2], bhi = state[3];
  float dp = dpp[0], g = gp[0];
  int nvec = E >> 2;
  int stride = gridDim.x * blockDim.x;
  unsigned acnt = 0;
  for (int iv = blockIdx.x * blockDim.x + threadIdx.x; iv < nvec; iv += stride) {
    float4 vv = reinterpret_cast<const float4*>(v)[iv];
    unsigned base = (unsigned)iv << 2;
    unsigned o0, o1, o2, o3;
    if (keys) {
      uint4 kk = reinterpret_cast<const uint4*>(keys)[iv];
      o0 = kk.x; o1 = kk.y; o2 = kk.z; o3 = kk.w;
    } else {
      o0 = compute_ou(base + 0u, vv.x, dp, g);
      o1 = compute_ou(base + 1u, vv.y, dp, g);
      o2 = compute_ou(base + 2u, vv.z, dp, g);
      o3 = compute_ou(base + 3u, vv.w, dp, g);
    }
    float4 oo;
    float vals[4] = {vv.x, vv.y, vv.z, vv.w};
    unsigned os[4] = {o0, o1, o2, o3};
    float res[4];
    #pragma unroll
    for (int j = 0; j < 4; ++j) {
      bool drop = os[j] > bhi;
      acnt += drop ? 1u : 0u;
      res[j] = drop ? 0.0f : vals[j];
      if (!drop && os[j] >= blo) {
        unsigned ec = compute_ou(base + (unsigned)j, vals[j], dp, g);
        unsigned q = atomicAdd(&state[4], 1u);
        if (q < LIST_CAP) {
          list[q] = make_uint2(ec, base + (unsigned)j);
          atomicAdd(&ehist1[ec >> 16], 1u);
        }
      }
    }
    oo.x = res[0]; oo.y = res[1]; oo.z = res[2]; oo.w = res[3];
    reinterpret_cast<float4*>(out)[iv] = oo;
  }
  if (blockIdx.x == 0) {
    for (int i = (nvec << 2) + threadIdx.x; i < E; i += 512) {
      float val = v[i];
      unsigned ou = keys ? keys[i] : compute_ou((unsigned)i, val, dp, g);
      bool drop = ou > bhi;
      acnt += drop ? 1u : 0u;
      float o = drop ? 0.0f : val;
      if (!drop && ou >= blo) {
        unsigned ec = compute_ou((unsigned)i, val, dp, g);
        unsigned q = atomicAdd(&state[4], 1u);
        if (q < LIST_CAP) {
          list[q] = make_uint2(ec, (unsigned)i);
          atomicAdd(&ehist1[ec >> 16], 1u);
        }
      }
      out[i] = o;
    }
  }
  atomicAdd(&sacc, acnt);
  __syncthreads();
  if (threadIdx.x == 0 && sacc) atomicAdd(&state[5], sacc);
}

// ============================================================================
// Fe: 65536-bin suffix select. level 0: kp = k - |A| -> state[7]=E1,
// state[8]=r. level 1: kp = state[8] -> state[9]=T_e code, state[10]=r2.
// ============================================================================
__global__ __launch_bounds__(1024) void find_e_kernel(
    const unsigned* __restrict__ eh, unsigned* __restrict__ state, int level) {
  __shared__ unsigned s[1024];
  int t = threadIdx.x;
  unsigned base = (unsigned)t * 64u;
  unsigned sum = 0;
  for (int j = 0; j < 64; ++j) sum += eh[base + j];
  s[t] = sum;
  __syncthreads();
  for (int off = 1; off < 1024; off <<= 1) {
    unsigned add = (t + off < 1024) ? s[t + off] : 0u;
    __syncthreads();
    s[t] += add;
    __syncthreads();
  }
  unsigned kp = (level == 0) ? (state[6] - state[5]) : state[8];
  if (kp == 0) {
    if (t == 0) {
      if (level == 0) { state[7] = 0xFFFFFFFFu; state[8] = 0u; }
      else           { state[9] = 0xFFFFFFFFu; state[10] = 0u; }
    }
    return;
  }
  unsigned above_next = (t < 1023) ? s[t + 1] : 0u;
  if (above_next < kp && kp <= s[t]) {
    unsigned above = above_next;
    for (int b = 63; b >= 0; --b) {
      unsigned c = eh[base + (unsigned)b];
      if (above < kp && kp <= above + c) {
        unsigned bin = base + (unsigned)b;
        if (level == 0) { state[7] = bin; state[8] = kp - above; }
        else { state[9] = (state[7] << 16) | bin; state[10] = kp - above; }
        break;
      }
      above += c;
    }
  }
}

// ============================================================================
// P5: second-level exact hist (low 16 bits of members of bin E1).
// ============================================================================
__global__ __launch_bounds__(256) void scatter2_kernel(
    const uint2* __restrict__ list, const unsigned* __restrict__ state,
    unsigned* __restrict__ ehist2) {
  unsigned M = min(state[4], LIST_CAP);
  unsigned E1 = state[7];
  for (unsigned e = blockIdx.x * 256 + threadIdx.x; e < M; e += gridDim.x * 256) {
    uint2 le = list[e];
    if ((le.x >> 16) == E1) atomicAdd(&ehist2[le.x & 0xFFFFu], 1u);
  }
}

// ============================================================================
// P6: drop band members with ecode > T_e; collect exact-tie indices.
// ============================================================================
__global__ __launch_bounds__(256) void band_drop_kernel(
    const uint2* __restrict__ list, unsigned* __restrict__ state,
    float* __restrict__ out, unsigned* __restrict__ mini) {
  unsigned M = min(state[4], LIST_CAP);
  unsigned Te = state[9];
  for (unsigned e = blockIdx.x * 256 + threadIdx.x; e < M; e += gridDim.x * 256) {
    uint2 le = list[e];
    if (le.x > Te) out[le.y] = 0.0f;
    else if (le.x == Te) {
      unsigned q = atomicAdd(&state[11], 1u);
      if (q < MINI_CAP) mini[q] = le.y;
    }
  }
}

// ============================================================================
// P7: among exact-key ties, drop the r2 with the smallest indices.
// ============================================================================
__global__ __launch_bounds__(1024) void mini_ties_kernel(
    const unsigned* __restrict__ mini, const unsigned* __restrict__ state,
    float* __restrict__ out) {
  unsigned m = min(state[11], MINI_CAP);
  unsigned r2 = state[10];
  if (r2 == 0 || m == 0) return;
  for (unsigned e = threadIdx.x; e < m; e += 1024) {
    unsigned my = mini[e];
    unsigned rank = 0;
    for (unsigned j = 0; j < m; ++j) rank += (mini[j] < my) ? 1u : 0u;
    if (rank < r2) out[my] = 0.0f;
  }
}

// ---------------- launch ----------------------------------------------------
extern "C" void kernel_launch(void* const* d_in, const int* in_sizes, int n_in,
                              void* d_out, int out_size, void* d_ws, size_t ws_size,
                              hipStream_t stream) {
  const float* v  = (const float*)d_in[0];
  const float* dp = (const float*)d_in[1];
  const float* g  = (const float*)d_in[2];
  const int* pct  = (const int*)d_in[3];
  float* out = (float*)d_out;
  int E = in_sizes[0];

  uint8_t* ws = (uint8_t*)d_ws;
  const size_t STATE_OFF = 0;                 // 64 words
  const size_t HIST_OFF  = 4096;              // 16 KiB
  const size_t EH1_OFF   = 65536;             // 256 KiB
  const size_t EH2_OFF   = 393216;            // 256 KiB
  const size_t MINI_OFF  = 786432;            // 16 KiB
  const size_t LIST_OFF  = (size_t)1 << 20;   // 2 MiB
  const size_t BH_OFF    = (size_t)4 << 20;   // NB * 16 KiB
  const size_t KEYS_OFF  = (size_t)24 << 20;  // E * 4 B

  int NB = 1024;
  if (ws_size < BH_OFF + (size_t)NB * 16384) {
    size_t avail = ws_size > BH_OFF ? (ws_size - BH_OFF) / 16384 : 0;
    NB = (int)(avail < 1024 ? avail : 1024);
    if (NB < 64) {  // cannot run selection; fail loudly via passthrough
      hipMemcpyAsync(out, v, (size_t)E * 4, hipMemcpyDeviceToDevice, stream);
      return;
    }
  }
  bool use_keys = ws_size >= KEYS_OFF + (size_t)E * 4;

  unsigned* state  = (unsigned*)(ws + STATE_OFF);
  unsigned* hist   = (unsigned*)(ws + HIST_OFF);
  unsigned* ehist1 = (unsigned*)(ws + EH1_OFF);
  unsigned* ehist2 = (unsigned*)(ws + EH2_OFF);
  unsigned* mini   = (unsigned*)(ws + MINI_OFF);
  uint2*    list   = (uint2*)(ws + LIST_OFF);
  unsigned* bh     = (unsigned*)(ws + BH_OFF);
  unsigned* keys   = use_keys ? (unsigned*)(ws + KEYS_OFF) : nullptr;
  float delta = use_keys ? DELTA : 0.0f;

  hipMemsetAsync(ws, 0, (size_t)1 << 20, stream);  // state+hist+ehists+mini

  key_hist1_kernel<<<NB, 512, 0, stream>>>(v, dp, g, keys, bh, E);
  reduce_hist_kernel<<<RED_SLICES * 16, 256, 0, stream>>>(bh, hist, NB);
  find1_kernel<<<1, 1024, 0, stream>>>(hist, state, pct, (long long)E);
  refine_hist_kernel<<<NB, 512, 0, stream>>>(v, dp, g, keys, state, bh, E);
  reduce_hist_kernel<<<RED_SLICES * 16, 256, 0, stream>>>(bh, hist, NB);
  find2_kernel<<<1, 1024, 0, stream>>>(hist, state, delta);
  output_kernel<<<2048, 512, 0, stream>>>(v, dp, g, keys, out, state, list, ehist1, E);
  find_e_kernel<<<1, 1024, 0, stream>>>(ehist1, state, 0);
  scatter2_kernel<<<256, 256, 0, stream>>>(list, state, ehist2);
  find_e_kernel<<<1, 1024, 0, stream>>>(ehist2, state, 1);
  band_drop_kernel<<<256, 256, 0, stream>>>(list, state, out, mini);
  mini_ties_kernel<<<1, 1024, 0, stream>>>(mini, state, out);
}